// Round 16
// baseline (2597.898 us; speedup 1.0000x reference)
//
#include <hip/hip_runtime.h>
#include <cstdint>
#include <cstddef>

#define N_NODES 5000
#define F_IN    7699
#define KP1     7712   // F_IN padded to mult of 32
#define KT1     241    // KP1/32
#define MP      5120   // rows padded to mult of 128
#define E_EDGES 40000
#define EFULL   45000  // E + N self loops
#define HC1     4096   // heads1*ch1
#define N1      8192   // xl|xr concat
#define HC2     1024
#define N2      2048
#define NOUT    128
#define GM256   (MP / 256)   // 20 M-blocks of 256
#define GM128   (MP / 128)   // 40 M-blocks of 128

typedef __bf16 bf16x8 __attribute__((ext_vector_type(8)));
typedef float  f32x4  __attribute__((ext_vector_type(4)));
typedef float  f32x16 __attribute__((ext_vector_type(16)));
typedef unsigned short u16x8 __attribute__((ext_vector_type(8)));
typedef _Float16 f16;
typedef _Float16 f16x8 __attribute__((ext_vector_type(8)));

using as1_uchar = unsigned char __attribute__((address_space(1)));
using as3_uchar = unsigned char __attribute__((address_space(3)));

__device__ __forceinline__ unsigned short f2bf(float f) {
  union { float f; unsigned int u; } v; v.f = f;
  return (unsigned short)((v.u + 0x7fffu + ((v.u >> 16) & 1u)) >> 16);
}
__device__ __forceinline__ float bf2f(unsigned short h) {
  union { unsigned int u; float f; } v; v.u = ((unsigned int)h) << 16;
  return v.f;
}

__device__ __forceinline__ void gload16(const void* g, void* l) {
  __builtin_amdgcn_global_load_lds(
      reinterpret_cast<const as1_uchar*>(reinterpret_cast<uintptr_t>(g)),
      reinterpret_cast<as3_uchar*>(reinterpret_cast<uintptr_t>(l)),
      16, 0, 0);
}

// Brick layout (global == LDS plane layout, conflict-free by construction):
// element (row r, k c) -> ((r>>7)*KT32 + (c>>5))*4096 + ((c>>3)&3)*1024 + (r&127)*8 + (c&7)

// ---------------- x -> hi/lo A-bricks ----------------

__global__ void k_split_x(const float* __restrict__ x, unsigned short* __restrict__ hi,
                          unsigned short* __restrict__ lo) {
  const int C8 = KP1 / 8;                       // 964
  int ci = blockIdx.x * 256 + threadIdx.x;
  if (ci >= MP * C8) return;
  int r = ci / C8, c8 = ci % C8;
  int c = c8 * 8;
  u16x8 hb, lb;
  #pragma unroll
  for (int j = 0; j < 8; ++j) {
    float v = 0.f;
    if (r < N_NODES && (c + j) < F_IN) v = x[(size_t)r * F_IN + c + j];
    unsigned short h = f2bf(v);
    hb[j] = h; lb[j] = f2bf(v - bf2f(h));
  }
  size_t off = ((size_t)((r >> 7) * KT1 + (c >> 5)) * 4 + ((c >> 3) & 3)) * 1024 + (r & 127) * 8;
  *(u16x8*)&hi[off] = hb;
  *(u16x8*)&lo[off] = lb;
}

// ---------------- W [K][Nsrc] f32 -> hi/lo B-bricks (transposed, k-padded) ----------------

__global__ void k_split_w(const float* __restrict__ W,
                          unsigned short* __restrict__ hi, unsigned short* __restrict__ lo,
                          int K, int Nsrc, int c0, int KT, int rowOffset) {
  __shared__ float tile[32][33];
  const int tid = threadIdx.x;
  const int kt = blockIdx.x;
  const int n0 = blockIdx.y * 32;
  #pragma unroll
  for (int i = tid >> 5; i < 32; i += 8) {
    int k = kt * 32 + i;
    tile[i][tid & 31] = (k < K) ? W[(size_t)k * Nsrc + c0 + n0 + (tid & 31)] : 0.f;
  }
  __syncthreads();
  if (tid < 128) {
    const int nn = tid >> 2, kc = (tid & 3) << 3;
    const int n = rowOffset + n0 + nn;
    u16x8 hb, lb;
    #pragma unroll
    for (int j = 0; j < 8; ++j) {
      float v = tile[kc + j][nn];
      unsigned short h = f2bf(v);
      hb[j] = h; lb[j] = f2bf(v - bf2f(h));
    }
    size_t off = ((size_t)((n >> 7) * KT + kt) * 4 + (kc >> 3)) * 1024 + (n & 127) * 8;
    *(u16x8*)&hi[off] = hb;
    *(u16x8*)&lo[off] = lb;
  }
}

// ======== k_gemm_big: r11 schedule DEEPENED to 5 buffers / 3-tile-in-flight DMA =============
// 256x128 tile, 8 waves, wave 64x64, 5 x 24KB bufs (120KB, 1 block/CU).
// Per half-step h: stage(h+4) [3 DMA/wave] -> reads(h+1) [8 b128] -> MFMA(h) [12, in regs]
// -> vmcnt(6) [drains exactly s(h+2), in flight 2.5 half-steps ~1100cyc, covers HBM]
// -> barrier. Read-ahead-1 safety identical to r11, shifted one step deeper.

template <int OF16>
__global__ __launch_bounds__(512, 1) void k_gemm_big(
    const unsigned short* __restrict__ Ahi, const unsigned short* __restrict__ Alo,
    const unsigned short* __restrict__ Bhi, const unsigned short* __restrict__ Blo,
    void* __restrict__ Cp, const float* __restrict__ bias0, const float* __restrict__ bias1,
    int halfN, int M, int Nc, int ldC, int KT32, int nbn)
{
  __shared__ __align__(16) unsigned short S[5 * 12288];   // 120KB

  const int tid = threadIdx.x;
  const int lane = tid & 63;
  const int w = tid >> 6;
  const int wm = w >> 1, wn = w & 1;

  const int nwg = gridDim.x;
  const int qq = nwg >> 3, rr = nwg & 7;
  const int xcd = blockIdx.x & 7, idx = blockIdx.x >> 3;
  const int wg = (xcd < rr ? xcd * (qq + 1) : rr * (qq + 1) + (xcd - rr) * qq) + idx;
  const int bm = wg / nbn, bn = wg % nbn;

  f32x16 acc[2][2] = {};

  const unsigned short* gsrc[3];
  int dd[3];
  #pragma unroll
  for (int s = 0; s < 3; ++s) {
    const int q = w * 3 + s;
    const unsigned short* base; int dOff; size_t rowoff; int p, hf;
    if (q < 8)       { int r_ = q;      base = Ahi; int t = r_ >> 2; p = (r_ >> 1) & 1; hf = r_ & 1;
                       dOff = t * 2048 + p * 1024 + hf * 512; rowoff = (size_t)(bm * 2 + t) * KT32 * 4096; }
    else if (q < 16) { int r_ = q - 8;  base = Alo; int t = r_ >> 2; p = (r_ >> 1) & 1; hf = r_ & 1;
                       dOff = 4096 + t * 2048 + p * 1024 + hf * 512; rowoff = (size_t)(bm * 2 + t) * KT32 * 4096; }
    else if (q < 20) { int r_ = q - 16; base = Bhi; p = (r_ >> 1) & 1; hf = r_ & 1;
                       dOff = 8192 + p * 1024 + hf * 512; rowoff = (size_t)bn * KT32 * 4096; }
    else             { int r_ = q - 20; base = Blo; p = (r_ >> 1) & 1; hf = r_ & 1;
                       dOff = 10240 + p * 1024 + hf * 512; rowoff = (size_t)bn * KT32 * 4096; }
    gsrc[s] = base + rowoff + p * 1024 + hf * 512 + lane * 8;
    dd[s] = dOff;
  }

  auto stage = [&](int kt16, int bufo) {
    const size_t o = (size_t)kt16 * 2048;
    #pragma unroll
    for (int s = 0; s < 3; ++s) gload16(gsrc[s] + o, &S[bufo + dd[s]]);
  };

  const int r5 = lane & 31, h5 = lane >> 5;
  const int tA = wm >> 1;
  const int rrA = (wm & 1) * 64;
  int ra[2], cb[2];
  #pragma unroll
  for (int i = 0; i < 2; ++i) ra[i] = tA * 2048 + h5 * 1024 + (rrA + i * 32 + r5) * 8;
  #pragma unroll
  for (int j = 0; j < 2; ++j) cb[j] = 8192 + h5 * 1024 + (wn * 64 + j * 32 + r5) * 8;

  struct Frags { bf16x8 ah[2], al[2], bh[2], bl[2]; };
  auto rdfr = [&](Frags& f, int bufo) {
    #pragma unroll
    for (int i = 0; i < 2; ++i) {
      f.ah[i] = *(const bf16x8*)&S[bufo + ra[i]];
      f.al[i] = *(const bf16x8*)&S[bufo + 4096 + ra[i]];
    }
    #pragma unroll
    for (int j = 0; j < 2; ++j) {
      f.bh[j] = *(const bf16x8*)&S[bufo + cb[j]];
      f.bl[j] = *(const bf16x8*)&S[bufo + 2048 + cb[j]];
    }
  };
  auto domfma = [&](Frags& f) {
    __builtin_amdgcn_s_setprio(1);
    #pragma unroll
    for (int j = 0; j < 2; ++j)
      #pragma unroll
      for (int i = 0; i < 2; ++i) {
        acc[i][j] = __builtin_amdgcn_mfma_f32_32x32x16_bf16(f.ah[i], f.bh[j], acc[i][j], 0, 0, 0);
        acc[i][j] = __builtin_amdgcn_mfma_f32_32x32x16_bf16(f.al[i], f.bh[j], acc[i][j], 0, 0, 0);
        acc[i][j] = __builtin_amdgcn_mfma_f32_32x32x16_bf16(f.ah[i], f.bl[j], acc[i][j], 0, 0, 0);
      }
    __builtin_amdgcn_s_setprio(0);
  };

  const int KT16 = KT32 * 2;   // even, >= 4 for all our K

  // prologue: tiles 0..3 staged (12 DMAs); vmcnt(6) drains s0,s1; read frags(0)
  stage(0, 0);
  stage(1, 12288);
  stage(2, 24576);
  stage(3, 36864);
  asm volatile("s_waitcnt vmcnt(6)" ::: "memory");
  __builtin_amdgcn_s_barrier();
  Frags fA, fB;
  rdfr(fA, 0);

  int o0 = 0, o1 = 12288, o2 = 24576, o3 = 36864, o4 = 49152;
  for (int kt = 0; kt < KT16; kt += 2) {
    // half kt: compute fA, read fB <- buf kt+1, stage kt+4 -> o4
    stage((kt + 4 < KT16) ? kt + 4 : KT16 - 1, o4);
    rdfr(fB, o1);
    domfma(fA);
    asm volatile("s_waitcnt vmcnt(6)" ::: "memory");   // drains s(kt+2)
    __builtin_amdgcn_s_barrier();
    // half kt+1: compute fB, read fA <- buf kt+2, stage kt+5 -> o0 (buf (kt+5)%5)
    stage((kt + 5 < KT16) ? kt + 5 : KT16 - 1, o0);
    rdfr(fA, o2);
    domfma(fB);
    asm volatile("s_waitcnt vmcnt(6)" ::: "memory");   // drains s(kt+3)
    __builtin_amdgcn_s_barrier();
    // rotate by 2 over 5: (o0,o1,o2,o3,o4) <- (o2,o3,o4,o0,o1)
    int t0 = o0, t1 = o1;
    o0 = o2; o1 = o3; o2 = o4; o3 = t0; o4 = t1;
  }

  #pragma unroll
  for (int i = 0; i < 2; ++i) {
    #pragma unroll
    for (int j = 0; j < 2; ++j) {
      const int gc = bn * 128 + wn * 64 + j * 32 + r5;
      if (gc < Nc) {
        const float bv = (gc < halfN) ? bias0[gc] : bias1[gc - halfN];
        #pragma unroll
        for (int reg = 0; reg < 16; ++reg) {
          const int gr = bm * 256 + wm * 64 + i * 32 + (reg & 3) + 8 * (reg >> 2) + 4 * h5;
          if (gr < M) {
            float v = acc[i][j][reg] + bv;
            if (OF16) ((f16*)Cp)[(size_t)gr * ldC + gc] = (f16)v;
            else      ((float*)Cp)[(size_t)gr * ldC + gc] = v;
          }
        }
      }
    }
  }
}

// ======== k_gemm_bb: r13 verbatim (128x128 tile, 4 waves, 2 blocks/CU) — GEMM2/GEMM3 ========

template <int OF16>
__global__ __launch_bounds__(256, 2) void k_gemm_bb(
    const unsigned short* __restrict__ Ahi, const unsigned short* __restrict__ Alo,
    const unsigned short* __restrict__ Bhi, const unsigned short* __restrict__ Blo,
    void* __restrict__ Cp, const float* __restrict__ bias0, const float* __restrict__ bias1,
    int halfN, int M, int Nc, int ldC, int KT32, int nbn)
{
  __shared__ __align__(16) unsigned short S[4 * 8192];   // 64KB

  const int tid = threadIdx.x;
  const int lane = tid & 63;
  const int w = tid >> 6;
  const int wm = w >> 1, wn = w & 1;

  const int nwg = gridDim.x;
  const int qq = nwg >> 3, rr = nwg & 7;
  const int xcd = blockIdx.x & 7, idx = blockIdx.x >> 3;
  const int wg = (xcd < rr ? xcd * (qq + 1) : rr * (qq + 1) + (xcd - rr) * qq) + idx;
  const int bm = wg / nbn, bn = wg % nbn;

  f32x16 acc[2][2] = {};

  const unsigned short* gbase = (w == 0) ? Ahi : (w == 1) ? Alo : (w == 2) ? Bhi : Blo;
  const int brow = (w < 2) ? bm : bn;
  const unsigned short* gsrc[4];
  int dd[4];
  #pragma unroll
  for (int s = 0; s < 4; ++s) {
    const int p = s >> 1, hf = s & 1;
    gsrc[s] = gbase + (size_t)brow * KT32 * 4096 + p * 1024 + hf * 512 + lane * 8;
    dd[s] = w * 2048 + p * 1024 + hf * 512;
  }

  auto stage = [&](int kt16, int bufo) {
    const size_t o = (size_t)kt16 * 2048;
    #pragma unroll
    for (int s = 0; s < 4; ++s) gload16(gsrc[s] + o, &S[bufo + dd[s]]);
  };

  const int r5 = lane & 31, h5 = lane >> 5;
  int ra[2], cb[2];
  #pragma unroll
  for (int i = 0; i < 2; ++i) ra[i] = h5 * 1024 + (wm * 64 + i * 32 + r5) * 8;
  #pragma unroll
  for (int j = 0; j < 2; ++j) cb[j] = 4096 + h5 * 1024 + (wn * 64 + j * 32 + r5) * 8;

  struct Frags { bf16x8 ah[2], al[2], bh[2], bl[2]; };
  auto rdfr = [&](Frags& f, int bufo) {
    #pragma unroll
    for (int i = 0; i < 2; ++i) {
      f.ah[i] = *(const bf16x8*)&S[bufo + ra[i]];
      f.al[i] = *(const bf16x8*)&S[bufo + 2048 + ra[i]];
    }
    #pragma unroll
    for (int j = 0; j < 2; ++j) {
      f.bh[j] = *(const bf16x8*)&S[bufo + cb[j]];
      f.bl[j] = *(const bf16x8*)&S[bufo + 2048 + cb[j]];
    }
  };
  auto domfma = [&](Frags& f) {
    __builtin_amdgcn_s_setprio(1);
    #pragma unroll
    for (int j = 0; j < 2; ++j)
      #pragma unroll
      for (int i = 0; i < 2; ++i) {
        acc[i][j] = __builtin_amdgcn_mfma_f32_32x32x16_bf16(f.ah[i], f.bh[j], acc[i][j], 0, 0, 0);
        acc[i][j] = __builtin_amdgcn_mfma_f32_32x32x16_bf16(f.al[i], f.bh[j], acc[i][j], 0, 0, 0);
        acc[i][j] = __builtin_amdgcn_mfma_f32_32x32x16_bf16(f.ah[i], f.bl[j], acc[i][j], 0, 0, 0);
      }
    __builtin_amdgcn_s_setprio(0);
  };

  const int KT16 = KT32 * 2;

  stage(0, 0);
  stage(1, 8192);
  stage(2, 16384);
  asm volatile("s_waitcnt vmcnt(4)" ::: "memory");
  __builtin_amdgcn_s_barrier();
  Frags fA, fB;
  rdfr(fA, 0);

  int o0 = 0, o1 = 8192, o2 = 16384, o3 = 24576;
  for (int kt = 0; kt < KT16; kt += 2) {
    stage((kt + 3 < KT16) ? kt + 3 : KT16 - 1, o3);
    rdfr(fB, o1);
    domfma(fA);
    asm volatile("s_waitcnt vmcnt(4)" ::: "memory");
    __builtin_amdgcn_s_barrier();
    stage((kt + 4 < KT16) ? kt + 4 : KT16 - 1, o0);
    rdfr(fA, o2);
    domfma(fB);
    asm volatile("s_waitcnt vmcnt(4)" ::: "memory");
    __builtin_amdgcn_s_barrier();
    int t0 = o0, t1 = o1;
    o0 = o2; o1 = o3; o2 = t0; o3 = t1;
  }

  #pragma unroll
  for (int i = 0; i < 2; ++i) {
    #pragma unroll
    for (int j = 0; j < 2; ++j) {
      const int gc = bn * 128 + wn * 64 + j * 32 + r5;
      if (gc < Nc) {
        const float bv = (gc < halfN) ? bias0[gc] : bias1[gc - halfN];
        #pragma unroll
        for (int reg = 0; reg < 16; ++reg) {
          const int gr = bm * 128 + wm * 64 + i * 32 + (reg & 3) + 8 * (reg >> 2) + 4 * h5;
          if (gr < M) {
            float v = acc[i][j][reg] + bv;
            if (OF16) ((f16*)Cp)[(size_t)gr * ldC + gc] = (f16)v;
            else      ((float*)Cp)[(size_t)gr * ldC + gc] = v;
          }
        }
      }
    }
  }
}

// ---------------- graph prep ----------------

__global__ void k_deg(const int* __restrict__ dst, const float* __restrict__ ea,
                      float* __restrict__ deg, float* __restrict__ lattr, int E) {
  int e = blockIdx.x * 256 + threadIdx.x;
  if (e >= E) return;
  int d = dst[e];
  atomicAdd(&deg[d], 1.f);
  atomicAdd(&lattr[d * 3 + 0], ea[e * 3 + 0]);
  atomicAdd(&lattr[d * 3 + 1], ea[e * 3 + 1]);
  atomicAdd(&lattr[d * 3 + 2], ea[e * 3 + 2]);
}

__global__ void k_lattr_fin(float* __restrict__ lattr, const float* __restrict__ deg, int n) {
  int i = blockIdx.x * 256 + threadIdx.x;
  if (i >= n) return;
  float dv = fmaxf(deg[i], 1.f);
  lattr[i * 3 + 0] /= dv; lattr[i * 3 + 1] /= dv; lattr[i * 3 + 2] /= dv;
}

__global__ void k_eafull(const float* __restrict__ ea, const float* __restrict__ lattr,
                         float* __restrict__ eaf, int E, int n) {
  int e = blockIdx.x * 256 + threadIdx.x;
  if (e >= E + n) return;
  const float* s = (e < E) ? &ea[(size_t)e * 3] : &lattr[(size_t)(e - E) * 3];
  eaf[e * 3 + 0] = s[0]; eaf[e * 3 + 1] = s[1]; eaf[e * 3 + 2] = s[2];
}

__global__ void k_count(const int* __restrict__ dst, int* __restrict__ cnt, int E, int n) {
  int e = blockIdx.x * 256 + threadIdx.x;
  if (e >= E + n) return;
  int d = (e < E) ? dst[e] : (e - E);
  atomicAdd(&cnt[d], 1);
}

__global__ void k_scan(const int* __restrict__ cnt, int* __restrict__ rowptr, int n) {
  int lane = threadIdx.x;   // 64 threads, 1 block
  int run = 0;
  for (int base = 0; base < n; base += 64) {
    int i = base + lane;
    int v = (i < n) ? cnt[i] : 0;
    #pragma unroll
    for (int off = 1; off < 64; off <<= 1) {
      int t = __shfl_up(v, off, 64);
      if (lane >= off) v += t;
    }
    if (i < n) rowptr[i + 1] = run + v;
    run += __shfl(v, 63, 64);
  }
  if (lane == 0) rowptr[0] = 0;
}

__global__ void k_fill(const int* __restrict__ dst, const int* __restrict__ rowptr,
                       int* __restrict__ fillc, int* __restrict__ elist, int E, int n) {
  int e = blockIdx.x * 256 + threadIdx.x;
  if (e >= E + n) return;
  int d = (e < E) ? dst[e] : (e - E);
  int pos = rowptr[d] + atomicAdd(&fillc[d], 1);
  elist[pos] = e;
}

// ---------------- FUSED attention: logit + online softmax + aggregation (per node) ----------

template <int H, int ITERS>
__global__ __launch_bounds__(256) void k_attn(
    const f16* __restrict__ xl, const f16* __restrict__ xr, int strideX,
    const float* __restrict__ eaf, const float* __restrict__ We, const float* __restrict__ att,
    const int* __restrict__ rowptr, const int* __restrict__ elist, const int* __restrict__ src,
    int E, const float* __restrict__ bias,
    unsigned short* __restrict__ ohi, unsigned short* __restrict__ olo, int KTo)
{
  constexpr int HC = ITERS * 256;
  const int n = blockIdx.x;
  const int tid = threadIdx.x;
  __shared__ float red[H][4];
  __shared__ float wbr[H], rbr[H], dsh[H];
  __shared__ float sx[HC];

  float xrv[ITERS], w0[ITERS], w1[ITERS], w2[ITERS], av[ITERS];
  const f16* rr = xr + (size_t)n * strideX;
  #pragma unroll
  for (int i = 0; i < ITERS; ++i) {
    const int hc = tid + (i << 8);
    xrv[i] = (float)rr[hc];
    w0[i] = We[hc]; w1[i] = We[HC + hc]; w2[i] = We[2 * HC + hc];
    av[i] = att[hc];
  }
  float acc[ITERS];
  #pragma unroll
  for (int i = 0; i < ITERS; ++i) acc[i] = 0.f;
  float mh = -1e30f, sh = 0.f;
  const int lane = tid & 63, wv = tid >> 6;
  const int start = rowptr[n], end = rowptr[n + 1];

  for (int p = start; p < end; ++p) {
    const int e = elist[p];
    const int s = (e < E) ? src[e] : (e - E);
    const float ea0 = eaf[e * 3 + 0], ea1 = eaf[e * 3 + 1], ea2 = eaf[e * 3 + 2];
    const f16* rl = xl + (size_t)s * strideX;
    float xlv[ITERS];
    float accL[H];
    #pragma unroll
    for (int h = 0; h < H; ++h) accL[h] = 0.f;
    #pragma unroll
    for (int i = 0; i < ITERS; ++i) {
      const int hc = tid + (i << 8);
      xlv[i] = (float)rl[hc];
      float v = xlv[i] + xrv[i] + ea0 * w0[i] + ea1 * w1[i] + ea2 * w2[i];
      v = (v > 0.f) ? v : 0.2f * v;
      accL[i >> 2] += v * av[i];
    }
    #pragma unroll
    for (int h = 0; h < H; ++h) {
      float v = accL[h];
      #pragma unroll
      for (int off = 32; off > 0; off >>= 1) v += __shfl_down(v, off, 64);
      if (lane == 0) red[h][wv] = v;
    }
    __syncthreads();
    if (tid < H) {
      const float l = red[tid][0] + red[tid][1] + red[tid][2] + red[tid][3];
      const float mn = fmaxf(mh, l);
      const float r_ = __expf(mh - mn), w_ = __expf(l - mn);
      sh = sh * r_ + w_;
      mh = mn;
      wbr[tid] = w_; rbr[tid] = r_;
    }
    __syncthreads();
    #pragma unroll
    for (int i = 0; i < ITERS; ++i) {
      const int h = (H == 4) ? (i >> 2) : 0;
      acc[i] = acc[i] * rbr[h] + wbr[h] * xlv[i];
    }
  }

  if (tid < H) dsh[tid] = sh + 1e-16f;
  __syncthreads();
  #pragma unroll
  for (int i = 0; i < ITERS; ++i) {
    const int hc = tid + (i << 8);
    const int h = (H == 4) ? (i >> 2) : 0;
    sx[hc] = acc[i] / dsh[h] + bias[hc];
  }
  __syncthreads();

  constexpr int NC8 = (HC / 8 + 255) / 256;
  #pragma unroll
  for (int q = 0; q < NC8; ++q) {
    const int c8 = tid + q * 256;
    if (c8 * 8 < HC) {
      u16x8 hb, lb;
      #pragma unroll
      for (int j = 0; j < 8; ++j) {
        float v = sx[c8 * 8 + j];
        unsigned short h = f2bf(v);
        hb[j] = h; lb[j] = f2bf(v - bf2f(h));
      }
      size_t off = ((size_t)((n >> 7) * KTo + (c8 >> 2)) * 4 + (c8 & 3)) * 1024 + (n & 127) * 8;
      *(u16x8*)&ohi[off] = hb;
      *(u16x8*)&olo[off] = lb;
    }
  }
}

// ---------------- launch ----------------

extern "C" void kernel_launch(void* const* d_in, const int* in_sizes, int n_in,
                              void* d_out, int out_size, void* d_ws, size_t ws_size,
                              hipStream_t stream) {
  const float* x    = (const float*)d_in[0];
  const int*   eidx = (const int*)d_in[1];
  const float* eattr= (const float*)d_in[2];
  const float* W1l  = (const float*)d_in[3];
  const float* b1l  = (const float*)d_in[4];
  const float* W1r  = (const float*)d_in[5];
  const float* b1r  = (const float*)d_in[6];
  const float* W1e  = (const float*)d_in[7];
  const float* att1 = (const float*)d_in[8];
  const float* bias1= (const float*)d_in[9];
  const float* W2l  = (const float*)d_in[10];
  const float* b2l  = (const float*)d_in[11];
  const float* W2r  = (const float*)d_in[12];
  const float* b2r  = (const float*)d_in[13];
  const float* W2e  = (const float*)d_in[14];
  const float* att2 = (const float*)d_in[15];
  const float* bias2= (const float*)d_in[16];
  const float* Wlin = (const float*)d_in[17];
  const float* blin = (const float*)d_in[18];
  float* out = (float*)d_out;

  char* ws = (char*)d_ws;
  const int* srcp = eidx;
  const int* dstp = eidx + E_EDGES;

  auto alignup = [](size_t v) { return (v + 255) & ~(size_t)255; };

  size_t mo = 0;
  auto take = [&](size_t sz) { size_t r = mo; mo = alignup(mo + sz); return r; };
  const size_t oLATTR = take((size_t)N_NODES * 3 * 4);
  const size_t oDEG   = take((size_t)N_NODES * 4);
  const size_t oEAF   = take((size_t)EFULL * 3 * 4);
  const size_t oCNT   = take((size_t)N_NODES * 4);
  const size_t oROW   = take((size_t)(N_NODES + 1) * 4);
  const size_t oFILL  = take((size_t)N_NODES * 4);
  const size_t oELIST = take((size_t)EFULL * 4);
  const size_t oLOGIT = take((size_t)EFULL * 4 * 4);   // kept for layout stability (unused)
  const size_t oMB    = take((size_t)N_NODES * 4 * 4);
  const size_t oDB    = take((size_t)N_NODES * 4 * 4);
  const size_t oXHI   = take((size_t)MP * KP1 * 2);            // A bricks hi: 79 MB
  const size_t oXLO   = take((size_t)MP * KP1 * 2);            // A bricks lo: 79 MB
  const size_t oXLR   = take((size_t)N_NODES * N1 * 2);        // xl|xr f16: 82 MB
  const size_t oBH    = take((size_t)N1 * KP1 * 2);            // B bricks hi: 126 MB
  const size_t oBL    = take((size_t)N1 * KP1 * 2);            // B bricks lo: 126 MB
  if (ws_size < mo) return;   // proven to fit (rounds 8-15 ran this layout)

  // overlays (regions free by write time)
  const size_t oH1HI = oXHI;                            // H1 bricks: 42 MB (in 79)
  const size_t oH1LO = oXLO;
  const size_t oXLR2 = oXLR;                            // f16 [5000][2048]: 20.5 MB
  const size_t oH2HI = oXLR + 32ull * 1024 * 1024;      // H2 bricks: 10.5 MB
  const size_t oH2LO = oXLR + 48ull * 1024 * 1024;
  const size_t oB2H  = oBH;                             // W2 bricks: 16.8 MB each
  const size_t oB2L  = oBH + 32ull * 1024 * 1024;
  const size_t oB3H  = oBH;                             // Wlin bricks (1 brickrow): 256 KB each
  const size_t oB3L  = oBH + 1ull * 1024 * 1024;

  unsigned short* XHI  = (unsigned short*)(ws + oXHI);
  unsigned short* XLO  = (unsigned short*)(ws + oXLO);
  f16*            XLR  = (f16*)(ws + oXLR);
  unsigned short* BH   = (unsigned short*)(ws + oBH);
  unsigned short* BL   = (unsigned short*)(ws + oBL);
  float*          LATTR= (float*)(ws + oLATTR);
  float*          DEG  = (float*)(ws + oDEG);
  float*          EAF  = (float*)(ws + oEAF);
  int*            CNT  = (int*)(ws + oCNT);
  int*            ROWP = (int*)(ws + oROW);
  int*            FILLC= (int*)(ws + oFILL);
  int*            ELIST= (int*)(ws + oELIST);
  unsigned short* H1HI = (unsigned short*)(ws + oH1HI);
  unsigned short* H1LO = (unsigned short*)(ws + oH1LO);
  f16*            XLR2 = (f16*)(ws + oXLR2);
  unsigned short* H2HI = (unsigned short*)(ws + oH2HI);
  unsigned short* H2LO = (unsigned short*)(ws + oH2LO);
  unsigned short* B2H  = (unsigned short*)(ws + oB2H);
  unsigned short* B2L  = (unsigned short*)(ws + oB2L);
  unsigned short* B3H  = (unsigned short*)(ws + oB3H);
  unsigned short* B3L  = (unsigned short*)(ws + oB3L);
  (void)oLOGIT; (void)oMB; (void)oDB;

  hipMemsetAsync(ws + oDEG,   0, (size_t)N_NODES * 4, stream);
  hipMemsetAsync(ws + oLATTR, 0, (size_t)N_NODES * 3 * 4, stream);
  hipMemsetAsync(ws + oCNT,   0, (size_t)N_NODES * 4, stream);
  hipMemsetAsync(ws + oFILL,  0, (size_t)N_NODES * 4, stream);

  const int gE  = (E_EDGES + 255) / 256;
  const int gEF = (EFULL + 255) / 256;
  const int gN  = (N_NODES + 255) / 256;

  // ---- graph structure ----
  k_deg<<<gE, 256, 0, stream>>>(dstp, eattr, DEG, LATTR, E_EDGES);
  k_lattr_fin<<<gN, 256, 0, stream>>>(LATTR, DEG, N_NODES);
  k_eafull<<<gEF, 256, 0, stream>>>(eattr, LATTR, EAF, E_EDGES, N_NODES);
  k_count<<<gEF, 256, 0, stream>>>(dstp, CNT, E_EDGES, N_NODES);
  k_scan<<<1, 64, 0, stream>>>(CNT, ROWP, N_NODES);
  k_fill<<<gEF, 256, 0, stream>>>(dstp, ROWP, FILLC, ELIST, E_EDGES, N_NODES);

  // ---- layer 1: merged W1l|W1r GEMM (deepened 5-buf pipeline) ----
  k_split_x<<<MP * (KP1 / 8) / 256, 256, 0, stream>>>(x, XHI, XLO);
  k_split_w<<<dim3(KT1, HC1 / 32), 256, 0, stream>>>(W1l, BH, BL, F_IN, HC1, 0, KT1, 0);
  k_split_w<<<dim3(KT1, HC1 / 32), 256, 0, stream>>>(W1r, BH, BL, F_IN, HC1, 0, KT1, HC1);
  k_gemm_big<1><<<GM256 * (N1 / 128), 512, 0, stream>>>(
      XHI, XLO, BH, BL, XLR, b1l, b1r, HC1, N_NODES, N1, N1, KT1, N1 / 128);

  // ---- layer 1 fused attention ----
  hipMemsetAsync(ws + oH1HI, 0, (size_t)MP * HC1 * 2, stream);
  hipMemsetAsync(ws + oH1LO, 0, (size_t)MP * HC1 * 2, stream);
  k_attn<4, 16><<<N_NODES, 256, 0, stream>>>(
      XLR, XLR + HC1, N1, EAF, W1e, att1, ROWP, ELIST, srcp, E_EDGES,
      bias1, H1HI, H1LO, HC1 / 32);

  // ---- layer 2 ----
  k_split_w<<<dim3(HC1 / 32, HC2 / 32), 256, 0, stream>>>(W2l, B2H, B2L, HC1, HC2, 0, HC1 / 32, 0);
  k_split_w<<<dim3(HC1 / 32, HC2 / 32), 256, 0, stream>>>(W2r, B2H, B2L, HC1, HC2, 0, HC1 / 32, HC2);
  k_gemm_bb<1><<<GM128 * (N2 / 128), 256, 0, stream>>>(
      H1HI, H1LO, B2H, B2L, XLR2, b2l, b2r, HC2, N_NODES, N2, N2, HC1 / 32, N2 / 128);

  hipMemsetAsync(ws + oH2HI, 0, (size_t)MP * HC2 * 2, stream);
  hipMemsetAsync(ws + oH2LO, 0, (size_t)MP * HC2 * 2, stream);
  k_attn<1, 4><<<N_NODES, 256, 0, stream>>>(
      XLR2, XLR2 + HC2, N2, EAF, W2e, att2, ROWP, ELIST, srcp, E_EDGES,
      bias2, H2HI, H2LO, HC2 / 32);

  // ---- final linear ----
  k_split_w<<<dim3(HC2 / 32, NOUT / 32), 256, 0, stream>>>(Wlin, B3H, B3L, HC2, NOUT, 0, HC2 / 32, 0);
  k_gemm_bb<0><<<GM128 * 1, 256, 0, stream>>>(
      H2HI, H2LO, B3H, B3L, out, blin, blin, NOUT, N_NODES, NOUT, NOUT, HC2 / 32, 1);
}

// Round 17
// 2542.625 us; speedup vs baseline: 1.0217x; 1.0217x over previous
//
#include <hip/hip_runtime.h>
#include <cstdint>
#include <cstddef>

#define N_NODES 5000
#define F_IN    7699
#define KP1     7712   // F_IN padded to mult of 32
#define KT1     241    // KP1/32
#define MP      5120   // rows padded to mult of 128
#define E_EDGES 40000
#define EFULL   45000  // E + N self loops
#define HC1     4096   // heads1*ch1
#define N1      8192   // xl|xr concat
#define HC2     1024
#define N2      2048
#define NOUT    128
#define GM256   (MP / 256)   // 20 M-blocks of 256
#define GM128   (MP / 128)   // 40 M-blocks of 128

typedef __bf16 bf16x8 __attribute__((ext_vector_type(8)));
typedef float  f32x4  __attribute__((ext_vector_type(4)));
typedef float  f32x16 __attribute__((ext_vector_type(16)));
typedef unsigned short u16x8 __attribute__((ext_vector_type(8)));
typedef _Float16 f16;
typedef _Float16 f16x8 __attribute__((ext_vector_type(8)));

using as1_uchar = unsigned char __attribute__((address_space(1)));
using as3_uchar = unsigned char __attribute__((address_space(3)));

__device__ __forceinline__ unsigned short f2bf(float f) {
  union { float f; unsigned int u; } v; v.f = f;
  return (unsigned short)((v.u + 0x7fffu + ((v.u >> 16) & 1u)) >> 16);
}
__device__ __forceinline__ float bf2f(unsigned short h) {
  union { unsigned int u; float f; } v; v.u = ((unsigned int)h) << 16;
  return v.f;
}

__device__ __forceinline__ void gload16(const void* g, void* l) {
  __builtin_amdgcn_global_load_lds(
      reinterpret_cast<const as1_uchar*>(reinterpret_cast<uintptr_t>(g)),
      reinterpret_cast<as3_uchar*>(reinterpret_cast<uintptr_t>(l)),
      16, 0, 0);
}

// Brick layout (global == LDS plane layout, conflict-free by construction):
// element (row r, k c) -> ((r>>7)*KT32 + (c>>5))*4096 + ((c>>3)&3)*1024 + (r&127)*8 + (c&7)

// ---------------- x -> hi/lo A-bricks ----------------

__global__ void k_split_x(const float* __restrict__ x, unsigned short* __restrict__ hi,
                          unsigned short* __restrict__ lo) {
  const int C8 = KP1 / 8;                       // 964
  int ci = blockIdx.x * 256 + threadIdx.x;
  if (ci >= MP * C8) return;
  int r = ci / C8, c8 = ci % C8;
  int c = c8 * 8;
  u16x8 hb, lb;
  #pragma unroll
  for (int j = 0; j < 8; ++j) {
    float v = 0.f;
    if (r < N_NODES && (c + j) < F_IN) v = x[(size_t)r * F_IN + c + j];
    unsigned short h = f2bf(v);
    hb[j] = h; lb[j] = f2bf(v - bf2f(h));
  }
  size_t off = ((size_t)((r >> 7) * KT1 + (c >> 5)) * 4 + ((c >> 3) & 3)) * 1024 + (r & 127) * 8;
  *(u16x8*)&hi[off] = hb;
  *(u16x8*)&lo[off] = lb;
}

// ---------------- W [K][Nsrc] f32 -> hi/lo B-bricks (transposed, k-padded) ----------------

__global__ void k_split_w(const float* __restrict__ W,
                          unsigned short* __restrict__ hi, unsigned short* __restrict__ lo,
                          int K, int Nsrc, int c0, int KT, int rowOffset) {
  __shared__ float tile[32][33];
  const int tid = threadIdx.x;
  const int kt = blockIdx.x;
  const int n0 = blockIdx.y * 32;
  #pragma unroll
  for (int i = tid >> 5; i < 32; i += 8) {
    int k = kt * 32 + i;
    tile[i][tid & 31] = (k < K) ? W[(size_t)k * Nsrc + c0 + n0 + (tid & 31)] : 0.f;
  }
  __syncthreads();
  if (tid < 128) {
    const int nn = tid >> 2, kc = (tid & 3) << 3;
    const int n = rowOffset + n0 + nn;
    u16x8 hb, lb;
    #pragma unroll
    for (int j = 0; j < 8; ++j) {
      float v = tile[kc + j][nn];
      unsigned short h = f2bf(v);
      hb[j] = h; lb[j] = f2bf(v - bf2f(h));
    }
    size_t off = ((size_t)((n >> 7) * KT + kt) * 4 + (kc >> 3)) * 1024 + (n & 127) * 8;
    *(u16x8*)&hi[off] = hb;
    *(u16x8*)&lo[off] = lb;
  }
}

// ======== k_gemm_big: r11 verbatim (256x128 tile, 8 waves, wave 64x64, 4x24KB bufs) =========

template <int OF16>
__global__ __launch_bounds__(512, 2) void k_gemm_big(
    const unsigned short* __restrict__ Ahi, const unsigned short* __restrict__ Alo,
    const unsigned short* __restrict__ Bhi, const unsigned short* __restrict__ Blo,
    void* __restrict__ Cp, const float* __restrict__ bias0, const float* __restrict__ bias1,
    int halfN, int M, int Nc, int ldC, int KT32, int nbn)
{
  __shared__ __align__(16) unsigned short S[4 * 12288];   // 96KB

  const int tid = threadIdx.x;
  const int lane = tid & 63;
  const int w = tid >> 6;
  const int wm = w >> 1, wn = w & 1;

  const int nwg = gridDim.x;
  const int qq = nwg >> 3, rr = nwg & 7;
  const int xcd = blockIdx.x & 7, idx = blockIdx.x >> 3;
  const int wg = (xcd < rr ? xcd * (qq + 1) : rr * (qq + 1) + (xcd - rr) * qq) + idx;
  const int bm = wg / nbn, bn = wg % nbn;

  f32x16 acc[2][2] = {};

  const unsigned short* gsrc[3];
  int dd[3];
  #pragma unroll
  for (int s = 0; s < 3; ++s) {
    const int q = w * 3 + s;
    const unsigned short* base; int dOff; size_t rowoff; int p, hf;
    if (q < 8)       { int r_ = q;      base = Ahi; int t = r_ >> 2; p = (r_ >> 1) & 1; hf = r_ & 1;
                       dOff = t * 2048 + p * 1024 + hf * 512; rowoff = (size_t)(bm * 2 + t) * KT32 * 4096; }
    else if (q < 16) { int r_ = q - 8;  base = Alo; int t = r_ >> 2; p = (r_ >> 1) & 1; hf = r_ & 1;
                       dOff = 4096 + t * 2048 + p * 1024 + hf * 512; rowoff = (size_t)(bm * 2 + t) * KT32 * 4096; }
    else if (q < 20) { int r_ = q - 16; base = Bhi; p = (r_ >> 1) & 1; hf = r_ & 1;
                       dOff = 8192 + p * 1024 + hf * 512; rowoff = (size_t)bn * KT32 * 4096; }
    else             { int r_ = q - 20; base = Blo; p = (r_ >> 1) & 1; hf = r_ & 1;
                       dOff = 10240 + p * 1024 + hf * 512; rowoff = (size_t)bn * KT32 * 4096; }
    gsrc[s] = base + rowoff + p * 1024 + hf * 512 + lane * 8;
    dd[s] = dOff;
  }

  auto stage = [&](int kt16, int bufo) {
    const size_t o = (size_t)kt16 * 2048;
    #pragma unroll
    for (int s = 0; s < 3; ++s) gload16(gsrc[s] + o, &S[bufo + dd[s]]);
  };

  const int r5 = lane & 31, h5 = lane >> 5;
  const int tA = wm >> 1;
  const int rrA = (wm & 1) * 64;
  int ra[2], cb[2];
  #pragma unroll
  for (int i = 0; i < 2; ++i) ra[i] = tA * 2048 + h5 * 1024 + (rrA + i * 32 + r5) * 8;
  #pragma unroll
  for (int j = 0; j < 2; ++j) cb[j] = 8192 + h5 * 1024 + (wn * 64 + j * 32 + r5) * 8;

  struct Frags { bf16x8 ah[2], al[2], bh[2], bl[2]; };
  auto rdfr = [&](Frags& f, int bufo) {
    #pragma unroll
    for (int i = 0; i < 2; ++i) {
      f.ah[i] = *(const bf16x8*)&S[bufo + ra[i]];
      f.al[i] = *(const bf16x8*)&S[bufo + 4096 + ra[i]];
    }
    #pragma unroll
    for (int j = 0; j < 2; ++j) {
      f.bh[j] = *(const bf16x8*)&S[bufo + cb[j]];
      f.bl[j] = *(const bf16x8*)&S[bufo + 2048 + cb[j]];
    }
  };
  auto domfma = [&](Frags& f) {
    __builtin_amdgcn_s_setprio(1);
    #pragma unroll
    for (int j = 0; j < 2; ++j)
      #pragma unroll
      for (int i = 0; i < 2; ++i) {
        acc[i][j] = __builtin_amdgcn_mfma_f32_32x32x16_bf16(f.ah[i], f.bh[j], acc[i][j], 0, 0, 0);
        acc[i][j] = __builtin_amdgcn_mfma_f32_32x32x16_bf16(f.al[i], f.bh[j], acc[i][j], 0, 0, 0);
        acc[i][j] = __builtin_amdgcn_mfma_f32_32x32x16_bf16(f.ah[i], f.bl[j], acc[i][j], 0, 0, 0);
      }
    __builtin_amdgcn_s_setprio(0);
  };

  const int KT16 = KT32 * 2;

  stage(0, 0);
  stage(1, 12288);
  stage(2, 24576);
  asm volatile("s_waitcnt vmcnt(3)" ::: "memory");
  __builtin_amdgcn_s_barrier();
  Frags fA, fB;
  rdfr(fA, 0);

  int o0 = 0, o1 = 12288, o2 = 24576, o3 = 36864;
  for (int kt = 0; kt < KT16; kt += 2) {
    stage((kt + 3 < KT16) ? kt + 3 : KT16 - 1, o3);
    rdfr(fB, o1);
    domfma(fA);
    asm volatile("s_waitcnt vmcnt(3)" ::: "memory");
    __builtin_amdgcn_s_barrier();
    stage((kt + 4 < KT16) ? kt + 4 : KT16 - 1, o0);
    rdfr(fA, o2);
    domfma(fB);
    asm volatile("s_waitcnt vmcnt(3)" ::: "memory");
    __builtin_amdgcn_s_barrier();
    int t0 = o0, t1 = o1;
    o0 = o2; o1 = o3; o2 = t0; o3 = t1;
  }

  #pragma unroll
  for (int i = 0; i < 2; ++i) {
    #pragma unroll
    for (int j = 0; j < 2; ++j) {
      const int gc = bn * 128 + wn * 64 + j * 32 + r5;
      if (gc < Nc) {
        const float bv = (gc < halfN) ? bias0[gc] : bias1[gc - halfN];
        #pragma unroll
        for (int reg = 0; reg < 16; ++reg) {
          const int gr = bm * 256 + wm * 64 + i * 32 + (reg & 3) + 8 * (reg >> 2) + 4 * h5;
          if (gr < M) {
            float v = acc[i][j][reg] + bv;
            if (OF16) ((f16*)Cp)[(size_t)gr * ldC + gc] = (f16)v;
            else      ((float*)Cp)[(size_t)gr * ldC + gc] = v;
          }
        }
      }
    }
  }
}

// ======== k_gemm_bb: r13 verbatim (128x128 tile, 4 waves, 2 blocks/CU) — GEMM2/GEMM3 ========

template <int OF16>
__global__ __launch_bounds__(256, 2) void k_gemm_bb(
    const unsigned short* __restrict__ Ahi, const unsigned short* __restrict__ Alo,
    const unsigned short* __restrict__ Bhi, const unsigned short* __restrict__ Blo,
    void* __restrict__ Cp, const float* __restrict__ bias0, const float* __restrict__ bias1,
    int halfN, int M, int Nc, int ldC, int KT32, int nbn)
{
  __shared__ __align__(16) unsigned short S[4 * 8192];   // 64KB

  const int tid = threadIdx.x;
  const int lane = tid & 63;
  const int w = tid >> 6;
  const int wm = w >> 1, wn = w & 1;

  const int nwg = gridDim.x;
  const int qq = nwg >> 3, rr = nwg & 7;
  const int xcd = blockIdx.x & 7, idx = blockIdx.x >> 3;
  const int wg = (xcd < rr ? xcd * (qq + 1) : rr * (qq + 1) + (xcd - rr) * qq) + idx;
  const int bm = wg / nbn, bn = wg % nbn;

  f32x16 acc[2][2] = {};

  const unsigned short* gbase = (w == 0) ? Ahi : (w == 1) ? Alo : (w == 2) ? Bhi : Blo;
  const int brow = (w < 2) ? bm : bn;
  const unsigned short* gsrc[4];
  int dd[4];
  #pragma unroll
  for (int s = 0; s < 4; ++s) {
    const int p = s >> 1, hf = s & 1;
    gsrc[s] = gbase + (size_t)brow * KT32 * 4096 + p * 1024 + hf * 512 + lane * 8;
    dd[s] = w * 2048 + p * 1024 + hf * 512;
  }

  auto stage = [&](int kt16, int bufo) {
    const size_t o = (size_t)kt16 * 2048;
    #pragma unroll
    for (int s = 0; s < 4; ++s) gload16(gsrc[s] + o, &S[bufo + dd[s]]);
  };

  const int r5 = lane & 31, h5 = lane >> 5;
  int ra[2], cb[2];
  #pragma unroll
  for (int i = 0; i < 2; ++i) ra[i] = h5 * 1024 + (wm * 64 + i * 32 + r5) * 8;
  #pragma unroll
  for (int j = 0; j < 2; ++j) cb[j] = 4096 + h5 * 1024 + (wn * 64 + j * 32 + r5) * 8;

  struct Frags { bf16x8 ah[2], al[2], bh[2], bl[2]; };
  auto rdfr = [&](Frags& f, int bufo) {
    #pragma unroll
    for (int i = 0; i < 2; ++i) {
      f.ah[i] = *(const bf16x8*)&S[bufo + ra[i]];
      f.al[i] = *(const bf16x8*)&S[bufo + 2048 + ra[i]];
    }
    #pragma unroll
    for (int j = 0; j < 2; ++j) {
      f.bh[j] = *(const bf16x8*)&S[bufo + cb[j]];
      f.bl[j] = *(const bf16x8*)&S[bufo + 2048 + cb[j]];
    }
  };
  auto domfma = [&](Frags& f) {
    __builtin_amdgcn_s_setprio(1);
    #pragma unroll
    for (int j = 0; j < 2; ++j)
      #pragma unroll
      for (int i = 0; i < 2; ++i) {
        acc[i][j] = __builtin_amdgcn_mfma_f32_32x32x16_bf16(f.ah[i], f.bh[j], acc[i][j], 0, 0, 0);
        acc[i][j] = __builtin_amdgcn_mfma_f32_32x32x16_bf16(f.al[i], f.bh[j], acc[i][j], 0, 0, 0);
        acc[i][j] = __builtin_amdgcn_mfma_f32_32x32x16_bf16(f.ah[i], f.bl[j], acc[i][j], 0, 0, 0);
      }
    __builtin_amdgcn_s_setprio(0);
  };

  const int KT16 = KT32 * 2;

  stage(0, 0);
  stage(1, 8192);
  stage(2, 16384);
  asm volatile("s_waitcnt vmcnt(4)" ::: "memory");
  __builtin_amdgcn_s_barrier();
  Frags fA, fB;
  rdfr(fA, 0);

  int o0 = 0, o1 = 8192, o2 = 16384, o3 = 24576;
  for (int kt = 0; kt < KT16; kt += 2) {
    stage((kt + 3 < KT16) ? kt + 3 : KT16 - 1, o3);
    rdfr(fB, o1);
    domfma(fA);
    asm volatile("s_waitcnt vmcnt(4)" ::: "memory");
    __builtin_amdgcn_s_barrier();
    stage((kt + 4 < KT16) ? kt + 4 : KT16 - 1, o0);
    rdfr(fA, o2);
    domfma(fB);
    asm volatile("s_waitcnt vmcnt(4)" ::: "memory");
    __builtin_amdgcn_s_barrier();
    int t0 = o0, t1 = o1;
    o0 = o2; o1 = o3; o2 = t0; o3 = t1;
  }

  #pragma unroll
  for (int i = 0; i < 2; ++i) {
    #pragma unroll
    for (int j = 0; j < 2; ++j) {
      const int gc = bn * 128 + wn * 64 + j * 32 + r5;
      if (gc < Nc) {
        const float bv = (gc < halfN) ? bias0[gc] : bias1[gc - halfN];
        #pragma unroll
        for (int reg = 0; reg < 16; ++reg) {
          const int gr = bm * 128 + wm * 64 + i * 32 + (reg & 3) + 8 * (reg >> 2) + 4 * h5;
          if (gr < M) {
            float v = acc[i][j][reg] + bv;
            if (OF16) ((f16*)Cp)[(size_t)gr * ldC + gc] = (f16)v;
            else      ((float*)Cp)[(size_t)gr * ldC + gc] = v;
          }
        }
      }
    }
  }
}

// ---------------- graph prep ----------------

__global__ void k_deg(const int* __restrict__ dst, const float* __restrict__ ea,
                      float* __restrict__ deg, float* __restrict__ lattr, int E) {
  int e = blockIdx.x * 256 + threadIdx.x;
  if (e >= E) return;
  int d = dst[e];
  atomicAdd(&deg[d], 1.f);
  atomicAdd(&lattr[d * 3 + 0], ea[e * 3 + 0]);
  atomicAdd(&lattr[d * 3 + 1], ea[e * 3 + 1]);
  atomicAdd(&lattr[d * 3 + 2], ea[e * 3 + 2]);
}

__global__ void k_lattr_fin(float* __restrict__ lattr, const float* __restrict__ deg, int n) {
  int i = blockIdx.x * 256 + threadIdx.x;
  if (i >= n) return;
  float dv = fmaxf(deg[i], 1.f);
  lattr[i * 3 + 0] /= dv; lattr[i * 3 + 1] /= dv; lattr[i * 3 + 2] /= dv;
}

__global__ void k_eafull(const float* __restrict__ ea, const float* __restrict__ lattr,
                         float* __restrict__ eaf, int E, int n) {
  int e = blockIdx.x * 256 + threadIdx.x;
  if (e >= E + n) return;
  const float* s = (e < E) ? &ea[(size_t)e * 3] : &lattr[(size_t)(e - E) * 3];
  eaf[e * 3 + 0] = s[0]; eaf[e * 3 + 1] = s[1]; eaf[e * 3 + 2] = s[2];
}

__global__ void k_count(const int* __restrict__ dst, int* __restrict__ cnt, int E, int n) {
  int e = blockIdx.x * 256 + threadIdx.x;
  if (e >= E + n) return;
  int d = (e < E) ? dst[e] : (e - E);
  atomicAdd(&cnt[d], 1);
}

__global__ void k_scan(const int* __restrict__ cnt, int* __restrict__ rowptr, int n) {
  int lane = threadIdx.x;   // 64 threads, 1 block
  int run = 0;
  for (int base = 0; base < n; base += 64) {
    int i = base + lane;
    int v = (i < n) ? cnt[i] : 0;
    #pragma unroll
    for (int off = 1; off < 64; off <<= 1) {
      int t = __shfl_up(v, off, 64);
      if (lane >= off) v += t;
    }
    if (i < n) rowptr[i + 1] = run + v;
    run += __shfl(v, 63, 64);
  }
  if (lane == 0) rowptr[0] = 0;
}

__global__ void k_fill(const int* __restrict__ dst, const int* __restrict__ rowptr,
                       int* __restrict__ fillc, int* __restrict__ elist, int E, int n) {
  int e = blockIdx.x * 256 + threadIdx.x;
  if (e >= E + n) return;
  int d = (e < E) ? dst[e] : (e - E);
  int pos = rowptr[d] + atomicAdd(&fillc[d], 1);
  elist[pos] = e;
}

// ---------------- FUSED attention, BARRIER-FREE (wave = head / wave = node) ----------------
// Thread owns 16 CONTIGUOUS elements (base = tl*16): for HC=4096/NPB=1, wave w == head w
// (tid*16>>10 == tid>>6) so the logit reduce is a pure 64-lane shfl reduce + in-wave
// broadcast — no LDS, no __syncthreads in the edge loop. Loads are 2 x f16x8 (coalesced).
// For HC=1024 (H=1): NPB=4 nodes per block, one wave per node. All lanes redundantly
// track (m, s) in-register. Output written thread-locally as hi/lo bricks.

template <int HC, int NPB>
__global__ __launch_bounds__(256) void k_attn(
    const f16* __restrict__ xl, const f16* __restrict__ xr, int strideX,
    const float* __restrict__ eaf, const float* __restrict__ We, const float* __restrict__ att,
    const int* __restrict__ rowptr, const int* __restrict__ elist, const int* __restrict__ src,
    int E, const float* __restrict__ bias,
    unsigned short* __restrict__ ohi, unsigned short* __restrict__ olo)
{
  constexpr int KTo = HC / 32;
  const int tl = (NPB == 1) ? (int)threadIdx.x : (int)(threadIdx.x & 63);
  const int n  = blockIdx.x * NPB + ((NPB == 1) ? 0 : (int)(threadIdx.x >> 6));
  const int base = tl * 16;

  float xrv[16], w0[16], w1[16], w2[16], av[16];
  {
    const f16* rr = xr + (size_t)n * strideX + base;
    f16x8 a0 = *(const f16x8*)rr, a1 = *(const f16x8*)(rr + 8);
    #pragma unroll
    for (int j = 0; j < 8; ++j) { xrv[j] = (float)a0[j]; xrv[8 + j] = (float)a1[j]; }
  }
  #pragma unroll
  for (int j = 0; j < 16; ++j) {
    w0[j] = We[base + j]; w1[j] = We[HC + base + j]; w2[j] = We[2 * HC + base + j];
    av[j] = att[base + j];
  }
  float acc[16];
  #pragma unroll
  for (int j = 0; j < 16; ++j) acc[j] = 0.f;
  float mh = -1e30f, sh = 0.f;

  const int start = rowptr[n], end = rowptr[n + 1];
  for (int p = start; p < end; ++p) {
    const int e = elist[p];
    const int s = (e < E) ? src[e] : (e - E);
    const float ea0 = eaf[e * 3 + 0], ea1 = eaf[e * 3 + 1], ea2 = eaf[e * 3 + 2];
    const f16* rl = xl + (size_t)s * strideX + base;
    f16x8 a0 = *(const f16x8*)rl, a1 = *(const f16x8*)(rl + 8);
    float xlv[16];
    #pragma unroll
    for (int j = 0; j < 8; ++j) { xlv[j] = (float)a0[j]; xlv[8 + j] = (float)a1[j]; }
    float part = 0.f;
    #pragma unroll
    for (int j = 0; j < 16; ++j) {
      float v = xlv[j] + xrv[j] + ea0 * w0[j] + ea1 * w1[j] + ea2 * w2[j];
      v = (v > 0.f) ? v : 0.2f * v;
      part += v * av[j];
    }
    #pragma unroll
    for (int off = 32; off > 0; off >>= 1) part += __shfl_down(part, off, 64);
    const float l = __shfl(part, 0, 64);       // broadcast head logit to all 64 lanes
    const float mn = fmaxf(mh, l);
    const float r_ = __expf(mh - mn), w_ = __expf(l - mn);
    sh = sh * r_ + w_;
    mh = mn;
    #pragma unroll
    for (int j = 0; j < 16; ++j) acc[j] = acc[j] * r_ + w_ * xlv[j];
  }

  const float inv = 1.f / (sh + 1e-16f);
  #pragma unroll
  for (int q = 0; q < 2; ++q) {
    u16x8 hb, lb;
    #pragma unroll
    for (int j = 0; j < 8; ++j) {
      float v = acc[q * 8 + j] * inv + bias[base + q * 8 + j];
      unsigned short h = f2bf(v);
      hb[j] = h; lb[j] = f2bf(v - bf2f(h));
    }
    const int c8 = 2 * tl + q;
    size_t off = ((size_t)((n >> 7) * KTo + (c8 >> 2)) * 4 + (c8 & 3)) * 1024 + (n & 127) * 8;
    *(u16x8*)&ohi[off] = hb;
    *(u16x8*)&olo[off] = lb;
  }
}

// ---------------- launch ----------------

extern "C" void kernel_launch(void* const* d_in, const int* in_sizes, int n_in,
                              void* d_out, int out_size, void* d_ws, size_t ws_size,
                              hipStream_t stream) {
  const float* x    = (const float*)d_in[0];
  const int*   eidx = (const int*)d_in[1];
  const float* eattr= (const float*)d_in[2];
  const float* W1l  = (const float*)d_in[3];
  const float* b1l  = (const float*)d_in[4];
  const float* W1r  = (const float*)d_in[5];
  const float* b1r  = (const float*)d_in[6];
  const float* W1e  = (const float*)d_in[7];
  const float* att1 = (const float*)d_in[8];
  const float* bias1= (const float*)d_in[9];
  const float* W2l  = (const float*)d_in[10];
  const float* b2l  = (const float*)d_in[11];
  const float* W2r  = (const float*)d_in[12];
  const float* b2r  = (const float*)d_in[13];
  const float* W2e  = (const float*)d_in[14];
  const float* att2 = (const float*)d_in[15];
  const float* bias2= (const float*)d_in[16];
  const float* Wlin = (const float*)d_in[17];
  const float* blin = (const float*)d_in[18];
  float* out = (float*)d_out;

  char* ws = (char*)d_ws;
  const int* srcp = eidx;
  const int* dstp = eidx + E_EDGES;

  auto alignup = [](size_t v) { return (v + 255) & ~(size_t)255; };

  size_t mo = 0;
  auto take = [&](size_t sz) { size_t r = mo; mo = alignup(mo + sz); return r; };
  const size_t oLATTR = take((size_t)N_NODES * 3 * 4);
  const size_t oDEG   = take((size_t)N_NODES * 4);
  const size_t oEAF   = take((size_t)EFULL * 3 * 4);
  const size_t oCNT   = take((size_t)N_NODES * 4);
  const size_t oROW   = take((size_t)(N_NODES + 1) * 4);
  const size_t oFILL  = take((size_t)N_NODES * 4);
  const size_t oELIST = take((size_t)EFULL * 4);
  const size_t oLOGIT = take((size_t)EFULL * 4 * 4);   // kept for layout stability (unused)
  const size_t oMB    = take((size_t)N_NODES * 4 * 4);
  const size_t oDB    = take((size_t)N_NODES * 4 * 4);
  const size_t oXHI   = take((size_t)MP * KP1 * 2);            // A bricks hi: 79 MB
  const size_t oXLO   = take((size_t)MP * KP1 * 2);            // A bricks lo: 79 MB
  const size_t oXLR   = take((size_t)N_NODES * N1 * 2);        // xl|xr f16: 82 MB
  const size_t oBH    = take((size_t)N1 * KP1 * 2);            // B bricks hi: 126 MB
  const size_t oBL    = take((size_t)N1 * KP1 * 2);            // B bricks lo: 126 MB
  if (ws_size < mo) return;   // proven to fit (rounds 8-16 ran this layout)

  // overlays (regions free by write time)
  const size_t oH1HI = oXHI;                            // H1 bricks: 42 MB (in 79)
  const size_t oH1LO = oXLO;
  const size_t oXLR2 = oXLR;                            // f16 [5000][2048]: 20.5 MB
  const size_t oH2HI = oXLR + 32ull * 1024 * 1024;      // H2 bricks: 10.5 MB
  const size_t oH2LO = oXLR + 48ull * 1024 * 1024;
  const size_t oB2H  = oBH;                             // W2 bricks: 16.8 MB each
  const size_t oB2L  = oBH + 32ull * 1024 * 1024;
  const size_t oB3H  = oBH;                             // Wlin bricks (1 brickrow): 256 KB each
  const size_t oB3L  = oBH + 1ull * 1024 * 1024;

  unsigned short* XHI  = (unsigned short*)(ws + oXHI);
  unsigned short* XLO  = (unsigned short*)(ws + oXLO);
  f16*            XLR  = (f16*)(ws + oXLR);
  unsigned short* BH   = (unsigned short*)(ws + oBH);
  unsigned short* BL   = (unsigned short*)(ws + oBL);
  float*          LATTR= (float*)(ws + oLATTR);
  float*          DEG  = (float*)(ws + oDEG);
  float*          EAF  = (float*)(ws + oEAF);
  int*            CNT  = (int*)(ws + oCNT);
  int*            ROWP = (int*)(ws + oROW);
  int*            FILLC= (int*)(ws + oFILL);
  int*            ELIST= (int*)(ws + oELIST);
  unsigned short* H1HI = (unsigned short*)(ws + oH1HI);
  unsigned short* H1LO = (unsigned short*)(ws + oH1LO);
  f16*            XLR2 = (f16*)(ws + oXLR2);
  unsigned short* H2HI = (unsigned short*)(ws + oH2HI);
  unsigned short* H2LO = (unsigned short*)(ws + oH2LO);
  unsigned short* B2H  = (unsigned short*)(ws + oB2H);
  unsigned short* B2L  = (unsigned short*)(ws + oB2L);
  unsigned short* B3H  = (unsigned short*)(ws + oB3H);
  unsigned short* B3L  = (unsigned short*)(ws + oB3L);
  (void)oLOGIT; (void)oMB; (void)oDB;

  hipMemsetAsync(ws + oDEG,   0, (size_t)N_NODES * 4, stream);
  hipMemsetAsync(ws + oLATTR, 0, (size_t)N_NODES * 3 * 4, stream);
  hipMemsetAsync(ws + oCNT,   0, (size_t)N_NODES * 4, stream);
  hipMemsetAsync(ws + oFILL,  0, (size_t)N_NODES * 4, stream);

  const int gE  = (E_EDGES + 255) / 256;
  const int gEF = (EFULL + 255) / 256;
  const int gN  = (N_NODES + 255) / 256;

  // ---- graph structure ----
  k_deg<<<gE, 256, 0, stream>>>(dstp, eattr, DEG, LATTR, E_EDGES);
  k_lattr_fin<<<gN, 256, 0, stream>>>(LATTR, DEG, N_NODES);
  k_eafull<<<gEF, 256, 0, stream>>>(eattr, LATTR, EAF, E_EDGES, N_NODES);
  k_count<<<gEF, 256, 0, stream>>>(dstp, CNT, E_EDGES, N_NODES);
  k_scan<<<1, 64, 0, stream>>>(CNT, ROWP, N_NODES);
  k_fill<<<gEF, 256, 0, stream>>>(dstp, ROWP, FILLC, ELIST, E_EDGES, N_NODES);

  // ---- layer 1: merged W1l|W1r GEMM (r11 kernel, 256x128 tiles) ----
  k_split_x<<<MP * (KP1 / 8) / 256, 256, 0, stream>>>(x, XHI, XLO);
  k_split_w<<<dim3(KT1, HC1 / 32), 256, 0, stream>>>(W1l, BH, BL, F_IN, HC1, 0, KT1, 0);
  k_split_w<<<dim3(KT1, HC1 / 32), 256, 0, stream>>>(W1r, BH, BL, F_IN, HC1, 0, KT1, HC1);
  k_gemm_big<1><<<GM256 * (N1 / 128), 512, 0, stream>>>(
      XHI, XLO, BH, BL, XLR, b1l, b1r, HC1, N_NODES, N1, N1, KT1, N1 / 128);

  // ---- layer 1 fused attention (barrier-free, wave = head) ----
  hipMemsetAsync(ws + oH1HI, 0, (size_t)MP * HC1 * 2, stream);
  hipMemsetAsync(ws + oH1LO, 0, (size_t)MP * HC1 * 2, stream);
  k_attn<HC1, 1><<<N_NODES, 256, 0, stream>>>(
      XLR, XLR + HC1, N1, EAF, W1e, att1, ROWP, ELIST, srcp, E_EDGES,
      bias1, H1HI, H1LO);

  // ---- layer 2 ----
  k_split_w<<<dim3(HC1 / 32, HC2 / 32), 256, 0, stream>>>(W2l, B2H, B2L, HC1, HC2, 0, HC1 / 32, 0);
  k_split_w<<<dim3(HC1 / 32, HC2 / 32), 256, 0, stream>>>(W2r, B2H, B2L, HC1, HC2, 0, HC1 / 32, HC2);
  k_gemm_bb<1><<<GM128 * (N2 / 128), 256, 0, stream>>>(
      H1HI, H1LO, B2H, B2L, XLR2, b2l, b2r, HC2, N_NODES, N2, N2, HC1 / 32, N2 / 128);

  hipMemsetAsync(ws + oH2HI, 0, (size_t)MP * HC2 * 2, stream);
  hipMemsetAsync(ws + oH2LO, 0, (size_t)MP * HC2 * 2, stream);
  k_attn<HC2, 4><<<(N_NODES + 3) / 4, 256, 0, stream>>>(
      XLR2, XLR2 + HC2, N2, EAF, W2e, att2, ROWP, ELIST, srcp, E_EDGES,
      bias2, H2HI, H2LO);

  // ---- final linear: Wlin = 1 brickrow (128 cols), fully written by k_split_w ----
  k_split_w<<<dim3(HC2 / 32, NOUT / 32), 256, 0, stream>>>(Wlin, B3H, B3L, HC2, NOUT, 0, HC2 / 32, 0);
  k_gemm_bb<0><<<GM128 * 1, 256, 0, stream>>>(
      H2HI, H2LO, B3H, B3L, out, blin, blin, NOUT, N_NODES, NOUT, NOUT, HC2 / 32, 1);
}

// Round 18
// 2494.090 us; speedup vs baseline: 1.0416x; 1.0195x over previous
//
#include <hip/hip_runtime.h>
#include <cstdint>
#include <cstddef>

#define N_NODES 5000
#define F_IN    7699
#define KP1     7712   // F_IN padded to mult of 32
#define KT1     241    // KP1/32
#define MP      5120   // rows padded to mult of 128
#define E_EDGES 40000
#define EFULL   45000  // E + N self loops
#define HC1     4096   // heads1*ch1
#define N1      8192   // xl|xr concat
#define HC2     1024
#define N2      2048
#define NOUT    128
#define GM256   (MP / 256)   // 20 M-blocks of 256
#define GM128   (MP / 128)   // 40 M-blocks of 128

typedef __bf16 bf16x8 __attribute__((ext_vector_type(8)));
typedef float  f32x4  __attribute__((ext_vector_type(4)));
typedef float  f32x16 __attribute__((ext_vector_type(16)));
typedef unsigned short u16x8 __attribute__((ext_vector_type(8)));
typedef _Float16 f16;
typedef _Float16 f16x8 __attribute__((ext_vector_type(8)));

using as1_uchar = unsigned char __attribute__((address_space(1)));
using as3_uchar = unsigned char __attribute__((address_space(3)));

__device__ __forceinline__ unsigned short f2bf(float f) {
  union { float f; unsigned int u; } v; v.f = f;
  return (unsigned short)((v.u + 0x7fffu + ((v.u >> 16) & 1u)) >> 16);
}
__device__ __forceinline__ float bf2f(unsigned short h) {
  union { unsigned int u; float f; } v; v.u = ((unsigned int)h) << 16;
  return v.f;
}

__device__ __forceinline__ void gload16(const void* g, void* l) {
  __builtin_amdgcn_global_load_lds(
      reinterpret_cast<const as1_uchar*>(reinterpret_cast<uintptr_t>(g)),
      reinterpret_cast<as3_uchar*>(reinterpret_cast<uintptr_t>(l)),
      16, 0, 0);
}

// Brick layout (global == LDS plane layout, conflict-free by construction):
// element (row r, k c) -> ((r>>7)*KT32 + (c>>5))*4096 + ((c>>3)&3)*1024 + (r&127)*8 + (c&7)

// ---------------- x -> hi/lo A-bricks ----------------

__global__ void k_split_x(const float* __restrict__ x, unsigned short* __restrict__ hi,
                          unsigned short* __restrict__ lo) {
  const int C8 = KP1 / 8;                       // 964
  int ci = blockIdx.x * 256 + threadIdx.x;
  if (ci >= MP * C8) return;
  int r = ci / C8, c8 = ci % C8;
  int c = c8 * 8;
  u16x8 hb, lb;
  #pragma unroll
  for (int j = 0; j < 8; ++j) {
    float v = 0.f;
    if (r < N_NODES && (c + j) < F_IN) v = x[(size_t)r * F_IN + c + j];
    unsigned short h = f2bf(v);
    hb[j] = h; lb[j] = f2bf(v - bf2f(h));
  }
  size_t off = ((size_t)((r >> 7) * KT1 + (c >> 5)) * 4 + ((c >> 3) & 3)) * 1024 + (r & 127) * 8;
  *(u16x8*)&hi[off] = hb;
  *(u16x8*)&lo[off] = lb;
}

// ---------------- W [K][Nsrc] f32 -> hi/lo B-bricks (transposed, k-padded) ----------------

__global__ void k_split_w(const float* __restrict__ W,
                          unsigned short* __restrict__ hi, unsigned short* __restrict__ lo,
                          int K, int Nsrc, int c0, int KT, int rowOffset) {
  __shared__ float tile[32][33];
  const int tid = threadIdx.x;
  const int kt = blockIdx.x;
  const int n0 = blockIdx.y * 32;
  #pragma unroll
  for (int i = tid >> 5; i < 32; i += 8) {
    int k = kt * 32 + i;
    tile[i][tid & 31] = (k < K) ? W[(size_t)k * Nsrc + c0 + n0 + (tid & 31)] : 0.f;
  }
  __syncthreads();
  if (tid < 128) {
    const int nn = tid >> 2, kc = (tid & 3) << 3;
    const int n = rowOffset + n0 + nn;
    u16x8 hb, lb;
    #pragma unroll
    for (int j = 0; j < 8; ++j) {
      float v = tile[kc + j][nn];
      unsigned short h = f2bf(v);
      hb[j] = h; lb[j] = f2bf(v - bf2f(h));
    }
    size_t off = ((size_t)((n >> 7) * KT + kt) * 4 + (kc >> 3)) * 1024 + (n & 127) * 8;
    *(u16x8*)&hi[off] = hb;
    *(u16x8*)&lo[off] = lb;
  }
}

// ======== k_gemm_big: r11 verbatim (256x128 tile, 8 waves, wave 64x64, 4x24KB bufs) =========

template <int OF16>
__global__ __launch_bounds__(512, 2) void k_gemm_big(
    const unsigned short* __restrict__ Ahi, const unsigned short* __restrict__ Alo,
    const unsigned short* __restrict__ Bhi, const unsigned short* __restrict__ Blo,
    void* __restrict__ Cp, const float* __restrict__ bias0, const float* __restrict__ bias1,
    int halfN, int M, int Nc, int ldC, int KT32, int nbn)
{
  __shared__ __align__(16) unsigned short S[4 * 12288];   // 96KB

  const int tid = threadIdx.x;
  const int lane = tid & 63;
  const int w = tid >> 6;
  const int wm = w >> 1, wn = w & 1;

  const int nwg = gridDim.x;
  const int qq = nwg >> 3, rr = nwg & 7;
  const int xcd = blockIdx.x & 7, idx = blockIdx.x >> 3;
  const int wg = (xcd < rr ? xcd * (qq + 1) : rr * (qq + 1) + (xcd - rr) * qq) + idx;
  const int bm = wg / nbn, bn = wg % nbn;

  f32x16 acc[2][2] = {};

  const unsigned short* gsrc[3];
  int dd[3];
  #pragma unroll
  for (int s = 0; s < 3; ++s) {
    const int q = w * 3 + s;
    const unsigned short* base; int dOff; size_t rowoff; int p, hf;
    if (q < 8)       { int r_ = q;      base = Ahi; int t = r_ >> 2; p = (r_ >> 1) & 1; hf = r_ & 1;
                       dOff = t * 2048 + p * 1024 + hf * 512; rowoff = (size_t)(bm * 2 + t) * KT32 * 4096; }
    else if (q < 16) { int r_ = q - 8;  base = Alo; int t = r_ >> 2; p = (r_ >> 1) & 1; hf = r_ & 1;
                       dOff = 4096 + t * 2048 + p * 1024 + hf * 512; rowoff = (size_t)(bm * 2 + t) * KT32 * 4096; }
    else if (q < 20) { int r_ = q - 16; base = Bhi; p = (r_ >> 1) & 1; hf = r_ & 1;
                       dOff = 8192 + p * 1024 + hf * 512; rowoff = (size_t)bn * KT32 * 4096; }
    else             { int r_ = q - 20; base = Blo; p = (r_ >> 1) & 1; hf = r_ & 1;
                       dOff = 10240 + p * 1024 + hf * 512; rowoff = (size_t)bn * KT32 * 4096; }
    gsrc[s] = base + rowoff + p * 1024 + hf * 512 + lane * 8;
    dd[s] = dOff;
  }

  auto stage = [&](int kt16, int bufo) {
    const size_t o = (size_t)kt16 * 2048;
    #pragma unroll
    for (int s = 0; s < 3; ++s) gload16(gsrc[s] + o, &S[bufo + dd[s]]);
  };

  const int r5 = lane & 31, h5 = lane >> 5;
  const int tA = wm >> 1;
  const int rrA = (wm & 1) * 64;
  int ra[2], cb[2];
  #pragma unroll
  for (int i = 0; i < 2; ++i) ra[i] = tA * 2048 + h5 * 1024 + (rrA + i * 32 + r5) * 8;
  #pragma unroll
  for (int j = 0; j < 2; ++j) cb[j] = 8192 + h5 * 1024 + (wn * 64 + j * 32 + r5) * 8;

  struct Frags { bf16x8 ah[2], al[2], bh[2], bl[2]; };
  auto rdfr = [&](Frags& f, int bufo) {
    #pragma unroll
    for (int i = 0; i < 2; ++i) {
      f.ah[i] = *(const bf16x8*)&S[bufo + ra[i]];
      f.al[i] = *(const bf16x8*)&S[bufo + 4096 + ra[i]];
    }
    #pragma unroll
    for (int j = 0; j < 2; ++j) {
      f.bh[j] = *(const bf16x8*)&S[bufo + cb[j]];
      f.bl[j] = *(const bf16x8*)&S[bufo + 2048 + cb[j]];
    }
  };
  auto domfma = [&](Frags& f) {
    __builtin_amdgcn_s_setprio(1);
    #pragma unroll
    for (int j = 0; j < 2; ++j)
      #pragma unroll
      for (int i = 0; i < 2; ++i) {
        acc[i][j] = __builtin_amdgcn_mfma_f32_32x32x16_bf16(f.ah[i], f.bh[j], acc[i][j], 0, 0, 0);
        acc[i][j] = __builtin_amdgcn_mfma_f32_32x32x16_bf16(f.al[i], f.bh[j], acc[i][j], 0, 0, 0);
        acc[i][j] = __builtin_amdgcn_mfma_f32_32x32x16_bf16(f.ah[i], f.bl[j], acc[i][j], 0, 0, 0);
      }
    __builtin_amdgcn_s_setprio(0);
  };

  const int KT16 = KT32 * 2;

  stage(0, 0);
  stage(1, 12288);
  stage(2, 24576);
  asm volatile("s_waitcnt vmcnt(3)" ::: "memory");
  __builtin_amdgcn_s_barrier();
  Frags fA, fB;
  rdfr(fA, 0);

  int o0 = 0, o1 = 12288, o2 = 24576, o3 = 36864;
  for (int kt = 0; kt < KT16; kt += 2) {
    stage((kt + 3 < KT16) ? kt + 3 : KT16 - 1, o3);
    rdfr(fB, o1);
    domfma(fA);
    asm volatile("s_waitcnt vmcnt(3)" ::: "memory");
    __builtin_amdgcn_s_barrier();
    stage((kt + 4 < KT16) ? kt + 4 : KT16 - 1, o0);
    rdfr(fA, o2);
    domfma(fB);
    asm volatile("s_waitcnt vmcnt(3)" ::: "memory");
    __builtin_amdgcn_s_barrier();
    int t0 = o0, t1 = o1;
    o0 = o2; o1 = o3; o2 = t0; o3 = t1;
  }

  #pragma unroll
  for (int i = 0; i < 2; ++i) {
    #pragma unroll
    for (int j = 0; j < 2; ++j) {
      const int gc = bn * 128 + wn * 64 + j * 32 + r5;
      if (gc < Nc) {
        const float bv = (gc < halfN) ? bias0[gc] : bias1[gc - halfN];
        #pragma unroll
        for (int reg = 0; reg < 16; ++reg) {
          const int gr = bm * 256 + wm * 64 + i * 32 + (reg & 3) + 8 * (reg >> 2) + 4 * h5;
          if (gr < M) {
            float v = acc[i][j][reg] + bv;
            if (OF16) ((f16*)Cp)[(size_t)gr * ldC + gc] = (f16)v;
            else      ((float*)Cp)[(size_t)gr * ldC + gc] = v;
          }
        }
      }
    }
  }
}

// ======== k_gemm_bb: r13 verbatim (128x128 tile, 4 waves, 2 blocks/CU) — GEMM2/GEMM3 ========

template <int OF16>
__global__ __launch_bounds__(256, 2) void k_gemm_bb(
    const unsigned short* __restrict__ Ahi, const unsigned short* __restrict__ Alo,
    const unsigned short* __restrict__ Bhi, const unsigned short* __restrict__ Blo,
    void* __restrict__ Cp, const float* __restrict__ bias0, const float* __restrict__ bias1,
    int halfN, int M, int Nc, int ldC, int KT32, int nbn)
{
  __shared__ __align__(16) unsigned short S[4 * 8192];   // 64KB

  const int tid = threadIdx.x;
  const int lane = tid & 63;
  const int w = tid >> 6;
  const int wm = w >> 1, wn = w & 1;

  const int nwg = gridDim.x;
  const int qq = nwg >> 3, rr = nwg & 7;
  const int xcd = blockIdx.x & 7, idx = blockIdx.x >> 3;
  const int wg = (xcd < rr ? xcd * (qq + 1) : rr * (qq + 1) + (xcd - rr) * qq) + idx;
  const int bm = wg / nbn, bn = wg % nbn;

  f32x16 acc[2][2] = {};

  const unsigned short* gbase = (w == 0) ? Ahi : (w == 1) ? Alo : (w == 2) ? Bhi : Blo;
  const int brow = (w < 2) ? bm : bn;
  const unsigned short* gsrc[4];
  int dd[4];
  #pragma unroll
  for (int s = 0; s < 4; ++s) {
    const int p = s >> 1, hf = s & 1;
    gsrc[s] = gbase + (size_t)brow * KT32 * 4096 + p * 1024 + hf * 512 + lane * 8;
    dd[s] = w * 2048 + p * 1024 + hf * 512;
  }

  auto stage = [&](int kt16, int bufo) {
    const size_t o = (size_t)kt16 * 2048;
    #pragma unroll
    for (int s = 0; s < 4; ++s) gload16(gsrc[s] + o, &S[bufo + dd[s]]);
  };

  const int r5 = lane & 31, h5 = lane >> 5;
  int ra[2], cb[2];
  #pragma unroll
  for (int i = 0; i < 2; ++i) ra[i] = h5 * 1024 + (wm * 64 + i * 32 + r5) * 8;
  #pragma unroll
  for (int j = 0; j < 2; ++j) cb[j] = 4096 + h5 * 1024 + (wn * 64 + j * 32 + r5) * 8;

  struct Frags { bf16x8 ah[2], al[2], bh[2], bl[2]; };
  auto rdfr = [&](Frags& f, int bufo) {
    #pragma unroll
    for (int i = 0; i < 2; ++i) {
      f.ah[i] = *(const bf16x8*)&S[bufo + ra[i]];
      f.al[i] = *(const bf16x8*)&S[bufo + 2048 + ra[i]];
    }
    #pragma unroll
    for (int j = 0; j < 2; ++j) {
      f.bh[j] = *(const bf16x8*)&S[bufo + cb[j]];
      f.bl[j] = *(const bf16x8*)&S[bufo + 2048 + cb[j]];
    }
  };
  auto domfma = [&](Frags& f) {
    __builtin_amdgcn_s_setprio(1);
    #pragma unroll
    for (int j = 0; j < 2; ++j)
      #pragma unroll
      for (int i = 0; i < 2; ++i) {
        acc[i][j] = __builtin_amdgcn_mfma_f32_32x32x16_bf16(f.ah[i], f.bh[j], acc[i][j], 0, 0, 0);
        acc[i][j] = __builtin_amdgcn_mfma_f32_32x32x16_bf16(f.al[i], f.bh[j], acc[i][j], 0, 0, 0);
        acc[i][j] = __builtin_amdgcn_mfma_f32_32x32x16_bf16(f.ah[i], f.bl[j], acc[i][j], 0, 0, 0);
      }
    __builtin_amdgcn_s_setprio(0);
  };

  const int KT16 = KT32 * 2;

  stage(0, 0);
  stage(1, 8192);
  stage(2, 16384);
  asm volatile("s_waitcnt vmcnt(4)" ::: "memory");
  __builtin_amdgcn_s_barrier();
  Frags fA, fB;
  rdfr(fA, 0);

  int o0 = 0, o1 = 8192, o2 = 16384, o3 = 24576;
  for (int kt = 0; kt < KT16; kt += 2) {
    stage((kt + 3 < KT16) ? kt + 3 : KT16 - 1, o3);
    rdfr(fB, o1);
    domfma(fA);
    asm volatile("s_waitcnt vmcnt(4)" ::: "memory");
    __builtin_amdgcn_s_barrier();
    stage((kt + 4 < KT16) ? kt + 4 : KT16 - 1, o0);
    rdfr(fA, o2);
    domfma(fB);
    asm volatile("s_waitcnt vmcnt(4)" ::: "memory");
    __builtin_amdgcn_s_barrier();
    int t0 = o0, t1 = o1;
    o0 = o2; o1 = o3; o2 = t0; o3 = t1;
  }

  #pragma unroll
  for (int i = 0; i < 2; ++i) {
    #pragma unroll
    for (int j = 0; j < 2; ++j) {
      const int gc = bn * 128 + wn * 64 + j * 32 + r5;
      if (gc < Nc) {
        const float bv = (gc < halfN) ? bias0[gc] : bias1[gc - halfN];
        #pragma unroll
        for (int reg = 0; reg < 16; ++reg) {
          const int gr = bm * 128 + wm * 64 + i * 32 + (reg & 3) + 8 * (reg >> 2) + 4 * h5;
          if (gr < M) {
            float v = acc[i][j][reg] + bv;
            if (OF16) ((f16*)Cp)[(size_t)gr * ldC + gc] = (f16)v;
            else      ((float*)Cp)[(size_t)gr * ldC + gc] = v;
          }
        }
      }
    }
  }
}

// ---------------- graph prep ----------------

__global__ void k_deg(const int* __restrict__ dst, const float* __restrict__ ea,
                      float* __restrict__ deg, float* __restrict__ lattr, int E) {
  int e = blockIdx.x * 256 + threadIdx.x;
  if (e >= E) return;
  int d = dst[e];
  atomicAdd(&deg[d], 1.f);
  atomicAdd(&lattr[d * 3 + 0], ea[e * 3 + 0]);
  atomicAdd(&lattr[d * 3 + 1], ea[e * 3 + 1]);
  atomicAdd(&lattr[d * 3 + 2], ea[e * 3 + 2]);
}

__global__ void k_lattr_fin(float* __restrict__ lattr, const float* __restrict__ deg, int n) {
  int i = blockIdx.x * 256 + threadIdx.x;
  if (i >= n) return;
  float dv = fmaxf(deg[i], 1.f);
  lattr[i * 3 + 0] /= dv; lattr[i * 3 + 1] /= dv; lattr[i * 3 + 2] /= dv;
}

__global__ void k_eafull(const float* __restrict__ ea, const float* __restrict__ lattr,
                         float* __restrict__ eaf, int E, int n) {
  int e = blockIdx.x * 256 + threadIdx.x;
  if (e >= E + n) return;
  const float* s = (e < E) ? &ea[(size_t)e * 3] : &lattr[(size_t)(e - E) * 3];
  eaf[e * 3 + 0] = s[0]; eaf[e * 3 + 1] = s[1]; eaf[e * 3 + 2] = s[2];
}

__global__ void k_count(const int* __restrict__ dst, int* __restrict__ cnt, int E, int n) {
  int e = blockIdx.x * 256 + threadIdx.x;
  if (e >= E + n) return;
  int d = (e < E) ? dst[e] : (e - E);
  atomicAdd(&cnt[d], 1);
}

__global__ void k_scan(const int* __restrict__ cnt, int* __restrict__ rowptr, int n) {
  int lane = threadIdx.x;   // 64 threads, 1 block
  int run = 0;
  for (int base = 0; base < n; base += 64) {
    int i = base + lane;
    int v = (i < n) ? cnt[i] : 0;
    #pragma unroll
    for (int off = 1; off < 64; off <<= 1) {
      int t = __shfl_up(v, off, 64);
      if (lane >= off) v += t;
    }
    if (i < n) rowptr[i + 1] = run + v;
    run += __shfl(v, 63, 64);
  }
  if (lane == 0) rowptr[0] = 0;
}

__global__ void k_fill(const int* __restrict__ dst, const int* __restrict__ rowptr,
                       int* __restrict__ fillc, int* __restrict__ elist, int E, int n) {
  int e = blockIdx.x * 256 + threadIdx.x;
  if (e >= E + n) return;
  int d = (e < E) ? dst[e] : (e - E);
  int pos = rowptr[d] + atomicAdd(&fillc[d], 1);
  elist[pos] = e;
}

// ---------------- FUSED attention, BARRIER-FREE (wave = head / wave = node) ----------------

template <int HC, int NPB>
__global__ __launch_bounds__(256) void k_attn(
    const f16* __restrict__ xl, const f16* __restrict__ xr, int strideX,
    const float* __restrict__ eaf, const float* __restrict__ We, const float* __restrict__ att,
    const int* __restrict__ rowptr, const int* __restrict__ elist, const int* __restrict__ src,
    int E, const float* __restrict__ bias,
    unsigned short* __restrict__ ohi, unsigned short* __restrict__ olo)
{
  constexpr int KTo = HC / 32;
  const int tl = (NPB == 1) ? (int)threadIdx.x : (int)(threadIdx.x & 63);
  const int n  = blockIdx.x * NPB + ((NPB == 1) ? 0 : (int)(threadIdx.x >> 6));
  const int base = tl * 16;

  float xrv[16], w0[16], w1[16], w2[16], av[16];
  {
    const f16* rr = xr + (size_t)n * strideX + base;
    f16x8 a0 = *(const f16x8*)rr, a1 = *(const f16x8*)(rr + 8);
    #pragma unroll
    for (int j = 0; j < 8; ++j) { xrv[j] = (float)a0[j]; xrv[8 + j] = (float)a1[j]; }
  }
  #pragma unroll
  for (int j = 0; j < 16; ++j) {
    w0[j] = We[base + j]; w1[j] = We[HC + base + j]; w2[j] = We[2 * HC + base + j];
    av[j] = att[base + j];
  }
  float acc[16];
  #pragma unroll
  for (int j = 0; j < 16; ++j) acc[j] = 0.f;
  float mh = -1e30f, sh = 0.f;

  const int start = rowptr[n], end = rowptr[n + 1];
  for (int p = start; p < end; ++p) {
    const int e = elist[p];
    const int s = (e < E) ? src[e] : (e - E);
    const float ea0 = eaf[e * 3 + 0], ea1 = eaf[e * 3 + 1], ea2 = eaf[e * 3 + 2];
    const f16* rl = xl + (size_t)s * strideX + base;
    f16x8 a0 = *(const f16x8*)rl, a1 = *(const f16x8*)(rl + 8);
    float xlv[16];
    #pragma unroll
    for (int j = 0; j < 8; ++j) { xlv[j] = (float)a0[j]; xlv[8 + j] = (float)a1[j]; }
    float part = 0.f;
    #pragma unroll
    for (int j = 0; j < 16; ++j) {
      float v = xlv[j] + xrv[j] + ea0 * w0[j] + ea1 * w1[j] + ea2 * w2[j];
      v = (v > 0.f) ? v : 0.2f * v;
      part += v * av[j];
    }
    #pragma unroll
    for (int off = 32; off > 0; off >>= 1) part += __shfl_down(part, off, 64);
    const float l = __shfl(part, 0, 64);       // broadcast head logit to all 64 lanes
    const float mn = fmaxf(mh, l);
    const float r_ = __expf(mh - mn), w_ = __expf(l - mn);
    sh = sh * r_ + w_;
    mh = mn;
    #pragma unroll
    for (int j = 0; j < 16; ++j) acc[j] = acc[j] * r_ + w_ * xlv[j];
  }

  const float inv = 1.f / (sh + 1e-16f);
  #pragma unroll
  for (int q = 0; q < 2; ++q) {
    u16x8 hb, lb;
    #pragma unroll
    for (int j = 0; j < 8; ++j) {
      float v = acc[q * 8 + j] * inv + bias[base + q * 8 + j];
      unsigned short h = f2bf(v);
      hb[j] = h; lb[j] = f2bf(v - bf2f(h));
    }
    const int c8 = 2 * tl + q;
    size_t off = ((size_t)((n >> 7) * KTo + (c8 >> 2)) * 4 + (c8 & 3)) * 1024 + (n & 127) * 8;
    *(u16x8*)&ohi[off] = hb;
    *(u16x8*)&olo[off] = lb;
  }
}

// ---------------- launch ----------------

extern "C" void kernel_launch(void* const* d_in, const int* in_sizes, int n_in,
                              void* d_out, int out_size, void* d_ws, size_t ws_size,
                              hipStream_t stream) {
  const float* x    = (const float*)d_in[0];
  const int*   eidx = (const int*)d_in[1];
  const float* eattr= (const float*)d_in[2];
  const float* W1l  = (const float*)d_in[3];
  const float* b1l  = (const float*)d_in[4];
  const float* W1r  = (const float*)d_in[5];
  const float* b1r  = (const float*)d_in[6];
  const float* W1e  = (const float*)d_in[7];
  const float* att1 = (const float*)d_in[8];
  const float* bias1= (const float*)d_in[9];
  const float* W2l  = (const float*)d_in[10];
  const float* b2l  = (const float*)d_in[11];
  const float* W2r  = (const float*)d_in[12];
  const float* b2r  = (const float*)d_in[13];
  const float* W2e  = (const float*)d_in[14];
  const float* att2 = (const float*)d_in[15];
  const float* bias2= (const float*)d_in[16];
  const float* Wlin = (const float*)d_in[17];
  const float* blin = (const float*)d_in[18];
  float* out = (float*)d_out;

  char* ws = (char*)d_ws;
  const int* srcp = eidx;
  const int* dstp = eidx + E_EDGES;

  auto alignup = [](size_t v) { return (v + 255) & ~(size_t)255; };

  size_t mo = 0;
  auto take = [&](size_t sz) { size_t r = mo; mo = alignup(mo + sz); return r; };
  const size_t oLATTR = take((size_t)N_NODES * 3 * 4);
  const size_t oDEG   = take((size_t)N_NODES * 4);
  const size_t oEAF   = take((size_t)EFULL * 3 * 4);
  const size_t oCNT   = take((size_t)N_NODES * 4);
  const size_t oROW   = take((size_t)(N_NODES + 1) * 4);
  const size_t oFILL  = take((size_t)N_NODES * 4);
  const size_t oELIST = take((size_t)EFULL * 4);
  const size_t oLOGIT = take((size_t)EFULL * 4 * 4);   // kept for layout stability (unused)
  const size_t oMB    = take((size_t)N_NODES * 4 * 4);
  const size_t oDB    = take((size_t)N_NODES * 4 * 4);
  const size_t oXHI   = take((size_t)MP * KP1 * 2);            // A bricks hi: 79 MB
  const size_t oXLO   = take((size_t)MP * KP1 * 2);            // A bricks lo: 79 MB
  const size_t oXLR   = take((size_t)N_NODES * N1 * 2);        // xl|xr f16: 82 MB
  const size_t oBH    = take((size_t)N1 * KP1 * 2);            // B bricks hi: 126 MB
  const size_t oBL    = take((size_t)N1 * KP1 * 2);            // B bricks lo: 126 MB
  if (ws_size < mo) return;   // proven to fit (rounds 8-17 ran this layout)

  // overlays (regions free by write time)
  const size_t oH1HI = oXHI;                            // H1 bricks: 42 MB (in 79)
  const size_t oH1LO = oXLO;
  const size_t oXLR2 = oXLR;                            // f16 [5000][2048]: 20.5 MB
  const size_t oH2HI = oXLR + 32ull * 1024 * 1024;      // H2 bricks: 10.5 MB
  const size_t oH2LO = oXLR + 48ull * 1024 * 1024;
  const size_t oB2H  = oBH;                             // W2 bricks: 16.8 MB each
  const size_t oB2L  = oBH + 32ull * 1024 * 1024;
  const size_t oB3H  = oBH;                             // Wlin bricks (1 brickrow): 256 KB each
  const size_t oB3L  = oBH + 1ull * 1024 * 1024;

  unsigned short* XHI  = (unsigned short*)(ws + oXHI);
  unsigned short* XLO  = (unsigned short*)(ws + oXLO);
  f16*            XLR  = (f16*)(ws + oXLR);
  unsigned short* BH   = (unsigned short*)(ws + oBH);
  unsigned short* BL   = (unsigned short*)(ws + oBL);
  float*          LATTR= (float*)(ws + oLATTR);
  float*          DEG  = (float*)(ws + oDEG);
  float*          EAF  = (float*)(ws + oEAF);
  int*            CNT  = (int*)(ws + oCNT);
  int*            ROWP = (int*)(ws + oROW);
  int*            FILLC= (int*)(ws + oFILL);
  int*            ELIST= (int*)(ws + oELIST);
  unsigned short* H1HI = (unsigned short*)(ws + oH1HI);
  unsigned short* H1LO = (unsigned short*)(ws + oH1LO);
  f16*            XLR2 = (f16*)(ws + oXLR2);
  unsigned short* H2HI = (unsigned short*)(ws + oH2HI);
  unsigned short* H2LO = (unsigned short*)(ws + oH2LO);
  unsigned short* B2H  = (unsigned short*)(ws + oB2H);
  unsigned short* B2L  = (unsigned short*)(ws + oB2L);
  unsigned short* B3H  = (unsigned short*)(ws + oB3H);
  unsigned short* B3L  = (unsigned short*)(ws + oB3L);
  (void)oLOGIT; (void)oMB; (void)oDB;

  hipMemsetAsync(ws + oDEG,   0, (size_t)N_NODES * 4, stream);
  hipMemsetAsync(ws + oLATTR, 0, (size_t)N_NODES * 3 * 4, stream);
  hipMemsetAsync(ws + oCNT,   0, (size_t)N_NODES * 4, stream);
  hipMemsetAsync(ws + oFILL,  0, (size_t)N_NODES * 4, stream);

  const int gE  = (E_EDGES + 255) / 256;
  const int gEF = (EFULL + 255) / 256;
  const int gN  = (N_NODES + 255) / 256;

  // ---- graph structure ----
  k_deg<<<gE, 256, 0, stream>>>(dstp, eattr, DEG, LATTR, E_EDGES);
  k_lattr_fin<<<gN, 256, 0, stream>>>(LATTR, DEG, N_NODES);
  k_eafull<<<gEF, 256, 0, stream>>>(eattr, LATTR, EAF, E_EDGES, N_NODES);
  k_count<<<gEF, 256, 0, stream>>>(dstp, CNT, E_EDGES, N_NODES);
  k_scan<<<1, 64, 0, stream>>>(CNT, ROWP, N_NODES);
  k_fill<<<gEF, 256, 0, stream>>>(dstp, ROWP, FILLC, ELIST, E_EDGES, N_NODES);

  // ---- layer 1: merged W1l|W1r GEMM (r11 kernel, 256x128 tiles) ----
  k_split_x<<<MP * (KP1 / 8) / 256, 256, 0, stream>>>(x, XHI, XLO);
  k_split_w<<<dim3(KT1, HC1 / 32), 256, 0, stream>>>(W1l, BH, BL, F_IN, HC1, 0, KT1, 0);
  k_split_w<<<dim3(KT1, HC1 / 32), 256, 0, stream>>>(W1r, BH, BL, F_IN, HC1, 0, KT1, HC1);
  k_gemm_big<1><<<GM256 * (N1 / 128), 512, 0, stream>>>(
      XHI, XLO, BH, BL, XLR, b1l, b1r, HC1, N_NODES, N1, N1, KT1, N1 / 128);

  // ---- layer 1 fused attention (barrier-free, wave = head) ----
  // NOTE: pad rows 5000..5119 of H bricks are left as garbage; A-row r only affects
  // C-row r in MFMA and all C-writes are guarded by gr < 5000, so no memset needed.
  k_attn<HC1, 1><<<N_NODES, 256, 0, stream>>>(
      XLR, XLR + HC1, N1, EAF, W1e, att1, ROWP, ELIST, srcp, E_EDGES,
      bias1, H1HI, H1LO);

  // ---- layer 2 ----
  k_split_w<<<dim3(HC1 / 32, HC2 / 32), 256, 0, stream>>>(W2l, B2H, B2L, HC1, HC2, 0, HC1 / 32, 0);
  k_split_w<<<dim3(HC1 / 32, HC2 / 32), 256, 0, stream>>>(W2r, B2H, B2L, HC1, HC2, 0, HC1 / 32, HC2);
  k_gemm_bb<1><<<GM128 * (N2 / 128), 256, 0, stream>>>(
      H1HI, H1LO, B2H, B2L, XLR2, b2l, b2r, HC2, N_NODES, N2, N2, HC1 / 32, N2 / 128);

  k_attn<HC2, 4><<<(N_NODES + 3) / 4, 256, 0, stream>>>(
      XLR2, XLR2 + HC2, N2, EAF, W2e, att2, ROWP, ELIST, srcp, E_EDGES,
      bias2, H2HI, H2LO);

  // ---- final linear: Wlin = 1 brickrow (128 cols), fully written by k_split_w ----
  k_split_w<<<dim3(HC2 / 32, NOUT / 32), 256, 0, stream>>>(Wlin, B3H, B3L, HC2, NOUT, 0, HC2 / 32, 0);
  k_gemm_bb<0><<<GM128 * 1, 256, 0, stream>>>(
      H2HI, H2LO, B3H, B3L, out, blin, blin, NOUT, N_NODES, NOUT, NOUT, HC2 / 32, 1);
}